// Round 12
// baseline (3501.376 us; speedup 1.0000x reference)
//
#include <hip/hip_runtime.h>
#include <hip/hip_bf16.h>

#define LEN   4096
#define EMB   300
#define HALF  256
#define G4    1024   // 4*HALF
#define HID   512
#define OUT_N 20

#if defined(__has_builtin)
#  if __has_builtin(__builtin_amdgcn_sdot4)
#    define HAVE_SDOT4 1
#  endif
#  if __has_builtin(__builtin_amdgcn_rcpf)
#    define RCPF(x) __builtin_amdgcn_rcpf(x)
#  endif
#endif
#ifndef RCPF
#  define RCPF(x) (1.0f/(x))
#endif

__device__ __forceinline__ int dot4(int a, int b, int c){
#ifdef HAVE_SDOT4
  return __builtin_amdgcn_sdot4(a, b, c, false);
#else
  c += (int)(signed char)(a)     * (int)(signed char)(b);
  c += (int)(signed char)(a>>8)  * (int)(signed char)(b>>8);
  c += (int)(signed char)(a>>16) * (int)(signed char)(b>>16);
  c += (int)(a>>24)              * (int)(b>>24);
  return c;
#endif
}

__device__ __forceinline__ float sigm_(float x){ return RCPF(1.f + __expf(-x)); }
__device__ __forceinline__ float tanh_(float x){ return 2.f*RCPF(1.f + __expf(-2.f*x)) - 1.f; }
__device__ __forceinline__ float bf2f(unsigned short u){ return __uint_as_float(((unsigned)u)<<16); }

// lane-pair swap (xor 1) via DPP quad_perm[1,0,3,2] = 0xB1 — pure VALU
__device__ __forceinline__ int dpp1i(int x){
  return __builtin_amdgcn_mov_dpp(x, 0xB1, 0xF, 0xF, true);
}
__device__ __forceinline__ float dpp1f(float x){
  return __int_as_float(dpp1i(__float_as_int(x)));
}

// ---------------- prep: quantize Whh rows to i8 + bias sums -----------------
__global__ void prep_quant(const float* __restrict__ WhhF, const float* __restrict__ WhhB,
    const float* __restrict__ bihF, const float* __restrict__ bhhF,
    const float* __restrict__ bihB, const float* __restrict__ bhhB,
    signed char* __restrict__ Wq, float* __restrict__ wsc, float* __restrict__ bsum)
{
  int r = blockIdx.x*256 + threadIdx.x;
  if (r >= 2*G4) return;
  int dir = r >> 10, row = r & 1023;
  const float4* Wr = (const float4*)((dir ? WhhB : WhhF) + (size_t)row*HALF);
  float m = 0.f;
  #pragma unroll 4
  for (int k=0;k<HALF/4;k++){
    float4 v = Wr[k];
    m = fmaxf(m, fmaxf(fmaxf(fabsf(v.x),fabsf(v.y)), fmaxf(fabsf(v.z),fabsf(v.w))));
  }
  float inv = 127.f / fmaxf(m, 1e-30f);
  int* q = (int*)(Wq + (size_t)r*HALF);
  #pragma unroll 4
  for (int k=0;k<HALF/4;k++){
    float4 v = Wr[k];
    int b0 = __float2int_rn(v.x*inv); b0 = b0>127?127:(b0<-127?-127:b0);
    int b1 = __float2int_rn(v.y*inv); b1 = b1>127?127:(b1<-127?-127:b1);
    int b2 = __float2int_rn(v.z*inv); b2 = b2>127?127:(b2<-127?-127:b2);
    int b3 = __float2int_rn(v.w*inv); b3 = b3>127?127:(b3<-127?-127:b3);
    q[k] = (b0&255) | ((b1&255)<<8) | ((b2&255)<<16) | ((b3&255)<<24);
  }
  wsc[r]  = (m/127.f)*(1.f/127.f);        // scale for (i32 dot) -> f32
  bsum[r] = dir ? (bihB[row]+bhhB[row]) : (bihF[row]+bhhF[row]);
}

// ---------------- Wv_ae = AE @ W_v_a^T + b_v_a  [20,512] --------------------
__global__ void wv_kernel(const float* __restrict__ AE, const float* __restrict__ Wv,
                          const float* __restrict__ bv, float* __restrict__ WvAE)
{
  __shared__ float ae[EMB];
  const int o = blockIdx.x, tid = threadIdx.x;
  for (int k=tid;k<EMB;k+=256) ae[k] = AE[(size_t)o*EMB+k];
  __syncthreads();
  for (int j=tid;j<HID;j+=256){
    const float* wr = Wv + (size_t)j*EMB;
    float d = 0.f;
    for (int k=0;k<EMB;k++) d += ae[k]*wr[k];
    WvAE[(size_t)o*HID + j] = d + bv[j];
  }
}

// ---- generic C[M,N] = A[idx(m),:K] * B[n,:K]^T + bias[n]; out f32 or bf16 ---
// gperm: permute output column g*256+j -> j*4+g (gate-interleaved pre layout)
__global__ __launch_bounds__(256) void gemm_tn(
    const float* __restrict__ A, int lda, const int* __restrict__ idx,
    const float* __restrict__ B, int ldb, const float* __restrict__ bias,
    float* __restrict__ Cf, __hip_bfloat16* __restrict__ Cb, int ldc,
    int M, int N, int K, int gperm)
{
  __shared__ __align__(16) float As[16][68];
  __shared__ __align__(16) float Bs[16][68];
  const int tid = threadIdx.x;
  const int bm = blockIdx.x<<6, bn = blockIdx.y<<6;
  const int lm = tid>>2;            // 0..63 row loaded by this thread
  const int lk = (tid&3)<<2;        // 0,4,8,12 k offset
  const int ty = tid>>4, tx = tid&15;
  int arow = bm + lm;
  if (idx) arow = idx[arow];
  const float* Ap = A + (size_t)arow*lda + lk;
  const float* Bp = B + (size_t)(bn+lm)*ldb + lk;
  float acc[4][4];
  #pragma unroll
  for (int i=0;i<4;i++)
    #pragma unroll
    for (int j=0;j<4;j++) acc[i][j]=0.f;

  for (int k0=0;k0<K;k0+=16){
    float4 av, bv;
    if (k0+16 <= K){
      av = *(const float4*)(Ap+k0);
      bv = *(const float4*)(Bp+k0);
    } else {
      float a0[4], b0[4];
      #pragma unroll
      for (int j=0;j<4;j++){
        int kk = k0+lk+j;
        a0[j] = (kk<K)? Ap[k0+j] : 0.f;
        b0[j] = (kk<K)? Bp[k0+j] : 0.f;
      }
      av = make_float4(a0[0],a0[1],a0[2],a0[3]);
      bv = make_float4(b0[0],b0[1],b0[2],b0[3]);
    }
    __syncthreads();
    As[lk+0][lm]=av.x; As[lk+1][lm]=av.y; As[lk+2][lm]=av.z; As[lk+3][lm]=av.w;
    Bs[lk+0][lm]=bv.x; Bs[lk+1][lm]=bv.y; Bs[lk+2][lm]=bv.z; Bs[lk+3][lm]=bv.w;
    __syncthreads();
    #pragma unroll
    for (int kk=0;kk<16;kk++){
      const float4 a = *(const float4*)(&As[kk][ty<<2]);
      const float4 b = *(const float4*)(&Bs[kk][tx<<2]);
      acc[0][0]+=a.x*b.x; acc[0][1]+=a.x*b.y; acc[0][2]+=a.x*b.z; acc[0][3]+=a.x*b.w;
      acc[1][0]+=a.y*b.x; acc[1][1]+=a.y*b.y; acc[1][2]+=a.y*b.z; acc[1][3]+=a.y*b.w;
      acc[2][0]+=a.z*b.x; acc[2][1]+=a.z*b.y; acc[2][2]+=a.z*b.z; acc[2][3]+=a.z*b.w;
      acc[3][0]+=a.w*b.x; acc[3][1]+=a.w*b.y; acc[3][2]+=a.w*b.z; acc[3][3]+=a.w*b.w;
    }
  }
  const int cm = bm+(ty<<2), cn = bn+(tx<<2);
  #pragma unroll
  for (int i=0;i<4;i++){
    #pragma unroll
    for (int j=0;j<4;j++){
      float v = acc[i][j] + (bias ? bias[cn+j] : 0.f);
      int col = cn+j;
      int pc = gperm ? (((col&255)<<2) | (col>>8)) : col;
      if (Cb) Cb[(size_t)(cm+i)*ldc + pc] = __float2bfloat16(v);
      else    Cf[(size_t)(cm+i)*ldc + pc] = v;
    }
  }
}

// -------------------- persistent bidirectional LSTM scan --------------------
// R11 structure (best: 3116us scan, absmax 0.00195). 2 blocks, 512 threads
// (8 waves, 2/SIMD). Thread (j=tid>>1, q2=tid&1) owns all 4 gate rows of unit
// j over k-half [128*q2,128*q2+128): 128 i8-packed weight ints as plain C
// locals. CHANGE vs R11: amdgpu_num_agpr(0) — forbid AGPR allocation so the
// spill-to-AGPR pass (which parks ~88 weight dwords in AGPRs and costs ~92
// v_accvgpr_read x 4cyc per step, ~37% of scan VALU work) has no destination;
// with the 256-arch-VGPR budget at 2 waves/EU the ~178-reg demand fits fully.
__global__ __attribute__((amdgpu_flat_work_group_size(512,512),
                          amdgpu_waves_per_eu(2,2),
                          amdgpu_num_vgpr(256),
                          amdgpu_num_agpr(0)))
void lstm_scan(
    const __hip_bfloat16* __restrict__ preF,   // [LEN][1024] gate-permuted [s][4j+g]
    const __hip_bfloat16* __restrict__ preB,
    const signed char* __restrict__ Wq,        // [2][1024][256] rows g*256+j
    const float* __restrict__ wsc,             // [2][1024]
    float* __restrict__ hs, float* __restrict__ ht)
{
  const int dir = blockIdx.x;
  const int tid = threadIdx.x;   // 0..511
  const int j  = tid >> 1;       // unit 0..255
  const int q2 = tid & 1;        // k-half 0..1
  __shared__ int hq[2][64];      // double-buffered 256 x i8 h

  const signed char* wp = Wq + (size_t)dir*G4*HALF;
  const int4* p0 = (const int4*)(wp + (size_t)(0*HALF + j)*HALF + q2*128);
  const int4* p1 = (const int4*)(wp + (size_t)(1*HALF + j)*HALF + q2*128);
  const int4* p2 = (const int4*)(wp + (size_t)(2*HALF + j)*HALF + q2*128);
  const int4* p3 = (const int4*)(wp + (size_t)(3*HALF + j)*HALF + q2*128);
  int4 wA0=p0[0],wA1=p0[1],wA2=p0[2],wA3=p0[3],wA4=p0[4],wA5=p0[5],wA6=p0[6],wA7=p0[7];
  int4 wB0=p1[0],wB1=p1[1],wB2=p1[2],wB3=p1[3],wB4=p1[4],wB5=p1[5],wB6=p1[6],wB7=p1[7];
  int4 wC0=p2[0],wC1=p2[1],wC2=p2[2],wC3=p2[3],wC4=p2[4],wC5=p2[5],wC6=p2[6],wC7=p2[7];
  int4 wD0=p3[0],wD1=p3[1],wD2=p3[2],wD3=p3[3],wD4=p3[4],wD5=p3[5],wD6=p3[6],wD7=p3[7];
#define PIN(v) asm volatile("" : "+v"(v.x),"+v"(v.y),"+v"(v.z),"+v"(v.w))
  PIN(wA0);PIN(wA1);PIN(wA2);PIN(wA3);PIN(wA4);PIN(wA5);PIN(wA6);PIN(wA7);
  PIN(wB0);PIN(wB1);PIN(wB2);PIN(wB3);PIN(wB4);PIN(wB5);PIN(wB6);PIN(wB7);
  PIN(wC0);PIN(wC1);PIN(wC2);PIN(wC3);PIN(wC4);PIN(wC5);PIN(wC6);PIN(wC7);
  PIN(wD0);PIN(wD1);PIN(wD2);PIN(wD3);PIN(wD4);PIN(wD5);PIN(wD6);PIN(wD7);
#undef PIN

  // lane q2 computes gates {2*q2, 2*q2+1}: lane0 -> (i,f), lane1 -> (g~,o)
  const float scA = wsc[dir*G4 + (2*q2+0)*HALF + j];
  const float scB = wsc[dir*G4 + (2*q2+1)*HALF + j];
  const float eK0 = q2 ? -2.f : -1.f;    // slot0: sigmoid (lane0) / tanh (lane1)
  const float aM0 = q2 ?  2.f :  1.f;
  const float aB0 = q2 ? -1.f :  0.f;

  const int t0 = dir ? (LEN-1) : 0;
  const int pstep = dir ? -(G4/2) : (G4/2);     // row stride in uints
  const unsigned* pp = (const unsigned*)(dir ? preB : preF) + (size_t)t0*(G4/2) + tid;
  float* hsp = hs + (size_t)t0*HID + dir*HALF + j;
  const int hstep = dir ? -HID : HID;

  if (tid < 64) hq[0][tid] = 0;
  float c = 0.f;
  unsigned pv = *pp;
  __syncthreads();

  for (int s=0;s<LEN;s++){
    unsigned pnext = 0;
    if (s < LEN-1){ pp += pstep; pnext = *pp; }
    const int4* hb = (const int4*)(&hq[s&1][0]) + q2*8;
    int a0=0,a1=0,a2=0,a3=0;
#define CHUNK(i, A,B,C,D) { int4 hv = hb[i]; \
    a0=dot4(A.x,hv.x,a0); a0=dot4(A.y,hv.y,a0); a0=dot4(A.z,hv.z,a0); a0=dot4(A.w,hv.w,a0); \
    a1=dot4(B.x,hv.x,a1); a1=dot4(B.y,hv.y,a1); a1=dot4(B.z,hv.z,a1); a1=dot4(B.w,hv.w,a1); \
    a2=dot4(C.x,hv.x,a2); a2=dot4(C.y,hv.y,a2); a2=dot4(C.z,hv.z,a2); a2=dot4(C.w,hv.w,a2); \
    a3=dot4(D.x,hv.x,a3); a3=dot4(D.y,hv.y,a3); a3=dot4(D.z,hv.z,a3); a3=dot4(D.w,hv.w,a3); }
    CHUNK(0, wA0,wB0,wC0,wD0)
    CHUNK(1, wA1,wB1,wC1,wD1)
    CHUNK(2, wA2,wB2,wC2,wD2)
    CHUNK(3, wA3,wB3,wC3,wD3)
    CHUNK(4, wA4,wB4,wC4,wD4)
    CHUNK(5, wA5,wB5,wC5,wD5)
    CHUNK(6, wA6,wB6,wC6,wD6)
    CHUNK(7, wA7,wB7,wC7,wD7)
#undef CHUNK
    // ---- DPP pair transpose-reduce over the lane pair ----
    // lane0 wants full a0,a1 (i,f); lane1 wants full a2,a3 (g~,o)
    int r0 = dpp1i(q2 ? a0 : a2);
    int s0 = (q2 ? a2 : a0) + r0;          // lane0: i pre-sum; lane1: g~ pre-sum
    int r1 = dpp1i(q2 ? a1 : a3);
    int s1 = (q2 ? a3 : a1) + r1;          // lane0: f pre-sum; lane1: o pre-sum
    // ---- 2 nonlinearities per thread ----
    float g0v = bf2f((unsigned short)(pv & 0xffffu))  + (float)s0*scA;
    float g1v = bf2f((unsigned short)(pv >> 16))      + (float)s1*scB;
    float y0  = RCPF(1.f + __expf(eK0 * g0v));
    float act0 = fmaf(aM0, y0, aB0);       // lane0: i ; lane1: g~
    float act1 = sigm_(g1v);               // lane0: f ; lane1: o
    // ---- bring (g~, o) to lane0 via DPP ----
    float gg = dpp1f(act0);                // lane0: g~
    float oo = dpp1f(act1);                // lane0: o
    if (q2 == 0){
      c = fmaf(act1, c, act0 * gg);
      float h = oo * tanh_(c);
      *hsp = h;
      ((signed char*)&hq[(s+1)&1][0])[j] = (signed char)__float2int_rn(h * 127.f);
      if (s == LEN-1) ht[dir*HALF + j] = h;
    }
    hsp += hstep;
    pv = pnext;
    __syncthreads();
  }
}

// ---------------- xw = ht @ W_x_a^T + b_x_a [512] ---------------------------
__global__ __launch_bounds__(512) void xw_kernel(const float* __restrict__ ht,
    const float* __restrict__ Wx, const float* __restrict__ bx, float* __restrict__ xw)
{
  __shared__ float h[HID];
  const int tid = threadIdx.x;
  h[tid] = ht[tid];
  __syncthreads();
  const float* wr = Wx + (size_t)tid*HID;
  float d = 0.f;
  for (int k=0;k<HID;k++) d += h[k]*wr[k];
  xw[tid] = d + bx[tid];
}

// ------- scores[o,l] = w_a . tanh(Wh_out[l] + Wv_ae[o]) + b_w_a -------------
__global__ __launch_bounds__(256) void scores_kernel(
    const float* __restrict__ WhOut, const float* __restrict__ WvAE,
    const float* __restrict__ wa, const float* __restrict__ bwa,
    float* __restrict__ scores)
{
  __shared__ float red[4];
  const int l = blockIdx.x, tid = threadIdx.x;
  const int lane = tid & 63, wv = tid >> 6;
  const float wl0 = WhOut[(size_t)l*HID + tid];
  const float wl1 = WhOut[(size_t)l*HID + 256 + tid];
  const float wa0 = wa[tid], wa1 = wa[256+tid];
  const float bb = bwa[0];
  for (int o=0;o<OUT_N;o++){
    float v = wa0*tanh_(wl0 + WvAE[o*HID+tid]) + wa1*tanh_(wl1 + WvAE[o*HID+256+tid]);
    #pragma unroll
    for (int m=32;m;m>>=1) v += __shfl_xor(v, m, 64);
    if (lane==0) red[wv] = v;
    __syncthreads();
    if (tid==0) scores[(size_t)o*LEN + l] = red[0]+red[1]+red[2]+red[3] + bb;
    __syncthreads();
  }
}

// ------- softmax over l (per o) + r[o] = weights @ output2 ------------------
__global__ __launch_bounds__(512) void softmax_wsum(
    const float* __restrict__ scores, const float* __restrict__ hs, float* __restrict__ ratt)
{
  __shared__ float sm[LEN];
  __shared__ float red[8];
  __shared__ float bc[2];
  const int o = blockIdx.x, tid = threadIdx.x;
  const int lane = tid & 63, wv = tid >> 6;
  for (int l=tid;l<LEN;l+=512) sm[l] = scores[(size_t)o*LEN + l];
  __syncthreads();
  float mx = -1e30f;
  for (int l=tid;l<LEN;l+=512) mx = fmaxf(mx, sm[l]);
  #pragma unroll
  for (int m=32;m;m>>=1) mx = fmaxf(mx, __shfl_xor(mx, m, 64));
  if (lane==0) red[wv] = mx;
  __syncthreads();
  if (tid==0){ float m0=red[0]; for (int i=1;i<8;i++) m0=fmaxf(m0,red[i]); bc[0]=m0; }
  __syncthreads();
  const float m0 = bc[0];
  float s = 0.f;
  for (int l=tid;l<LEN;l+=512){ float e = __expf(sm[l]-m0); sm[l]=e; s+=e; }
  #pragma unroll
  for (int m=32;m;m>>=1) s += __shfl_xor(s, m, 64);
  if (lane==0) red[wv] = s;
  __syncthreads();
  if (tid==0){ float z=0.f; for (int i=0;i<8;i++) z+=red[i]; bc[1] = 1.f/z; }
  __syncthreads();
  const float rz = bc[1];
  float acc = 0.f;
  const float* hp = hs + tid;
  for (int l=0;l<LEN;l++) acc += sm[l]*hp[(size_t)l*HID];
  ratt[(size_t)o*HID + tid] = acc*rz;
}

// ------- out[o] = sigmoid( dec_W[o] . tanh(r W_p^T + b_p + xw) + dec_b ) ----
__global__ __launch_bounds__(256) void final_kernel(
    const float* __restrict__ ratt, const float* __restrict__ Wp, const float* __restrict__ bp,
    const float* __restrict__ xw, const float* __restrict__ decW, const float* __restrict__ decb,
    float* __restrict__ outp)
{
  __shared__ float rv[HID];
  __shared__ float rr[HID];
  __shared__ float red[4];
  const int o = blockIdx.x, tid = threadIdx.x;
  const int lane = tid & 63, wv = tid >> 6;
  rv[tid]     = ratt[(size_t)o*HID + tid];
  rv[256+tid] = ratt[(size_t)o*HID + 256 + tid];
  __syncthreads();
  #pragma unroll
  for (int jj=0;jj<2;jj++){
    int j = tid + jj*256;
    const float* wr = Wp + (size_t)j*HID;
    float d = 0.f;
    for (int k=0;k<HID;k++) d += rv[k]*wr[k];
    rr[j] = tanh_(d + bp[j] + xw[j]);
  }
  __syncthreads();
  float v = rr[tid]*decW[(size_t)o*HID+tid] + rr[256+tid]*decW[(size_t)o*HID+256+tid];
  #pragma unroll
  for (int m=32;m;m>>=1) v += __shfl_xor(v, m, 64);
  if (lane==0) red[wv] = v;
  __syncthreads();
  if (tid==0) outp[o] = sigm_(red[0]+red[1]+red[2]+red[3] + decb[o]);
}

// ---------------------------------------------------------------------------
extern "C" void kernel_launch(void* const* d_in, const int* in_sizes, int n_in,
                              void* d_out, int out_size, void* d_ws, size_t ws_size,
                              hipStream_t stream)
{
  (void)in_sizes; (void)n_in; (void)out_size; (void)ws_size;
  const int*   sent  = (const int*)  d_in[0];
  const float* embed = (const float*)d_in[1];
  const float* WihF  = (const float*)d_in[2];
  const float* WhhF  = (const float*)d_in[3];
  const float* bihF  = (const float*)d_in[4];
  const float* bhhF  = (const float*)d_in[5];
  const float* WihB  = (const float*)d_in[6];
  const float* WhhB  = (const float*)d_in[7];
  const float* bihB  = (const float*)d_in[8];
  const float* bhhB  = (const float*)d_in[9];
  const float* AE    = (const float*)d_in[10];
  const float* W_h   = (const float*)d_in[11];
  const float* b_h   = (const float*)d_in[12];
  const float* W_v   = (const float*)d_in[13];
  const float* b_v   = (const float*)d_in[14];
  const float* w_a   = (const float*)d_in[15];
  const float* b_w   = (const float*)d_in[16];
  const float* W_p   = (const float*)d_in[17];
  const float* b_p   = (const float*)d_in[18];
  const float* W_x   = (const float*)d_in[19];
  const float* b_x   = (const float*)d_in[20];
  const float* decW  = (const float*)d_in[21];
  const float* decb  = (const float*)d_in[22];
  float* outp = (float*)d_out;

  char* ws = (char*)d_ws;
  size_t off = 0;
  auto alloc = [&](size_t n){ size_t p = off; off += (n + 255) & ~(size_t)255; return p; };
  __hip_bfloat16* preF  = (__hip_bfloat16*)(ws + alloc((size_t)LEN*G4*2));
  __hip_bfloat16* preB  = (__hip_bfloat16*)(ws + alloc((size_t)LEN*G4*2));
  float*          hsbuf = (float*)        (ws + alloc((size_t)LEN*HID*4));
  float*          WhOut = (float*)        (ws + alloc((size_t)LEN*HID*4));
  signed char*    Wq    = (signed char*)  (ws + alloc((size_t)2*G4*HALF));
  float*          wsc   = (float*)        (ws + alloc((size_t)2*G4*4));
  float*          bsum  = (float*)        (ws + alloc((size_t)2*G4*4));
  float*          htv   = (float*)        (ws + alloc((size_t)HID*4));
  float*          WvAE  = (float*)        (ws + alloc((size_t)OUT_N*HID*4));
  float*          xw    = (float*)        (ws + alloc((size_t)HID*4));
  float*          scor  = (float*)        (ws + alloc((size_t)OUT_N*LEN*4));
  float*          ratt  = (float*)        (ws + alloc((size_t)OUT_N*HID*4));

  // prep
  prep_quant<<<8, 256, 0, stream>>>(WhhF, WhhB, bihF, bhhF, bihB, bhhB, Wq, wsc, bsum);
  wv_kernel<<<OUT_N, 256, 0, stream>>>(AE, W_v, b_v, WvAE);

  // pre = gather(embed, sent) @ Wih^T + (bih+bhh), bf16, gate-permuted cols
  gemm_tn<<<dim3(LEN/64, G4/64), 256, 0, stream>>>(
      embed, EMB, sent, WihF, EMB, bsum,        nullptr, preF, G4, LEN, G4, EMB, 1);
  gemm_tn<<<dim3(LEN/64, G4/64), 256, 0, stream>>>(
      embed, EMB, sent, WihB, EMB, bsum + G4,   nullptr, preB, G4, LEN, G4, EMB, 1);

  // sequential bidirectional scan (2 persistent blocks, 512 threads each)
  lstm_scan<<<2, 512, 0, stream>>>(preF, preB, Wq, wsc, hsbuf, htv);

  // Wh_out = output2 @ W_h_a^T + b_h_a
  gemm_tn<<<dim3(LEN/64, HID/64), 256, 0, stream>>>(
      hsbuf, HID, nullptr, W_h, HID, b_h, WhOut, nullptr, HID, LEN, HID, HID, 0);

  xw_kernel<<<1, 512, 0, stream>>>(htv, W_x, b_x, xw);
  scores_kernel<<<LEN, 256, 0, stream>>>(WhOut, WvAE, w_a, b_w, scor);
  softmax_wsum<<<OUT_N, 512, 0, stream>>>(scor, hsbuf, ratt);
  final_kernel<<<OUT_N, 256, 0, stream>>>(ratt, W_p, b_p, xw, decW, decb, outp);
}

// Round 13
// 3492.153 us; speedup vs baseline: 1.0026x; 1.0026x over previous
//
#include <hip/hip_runtime.h>
#include <hip/hip_bf16.h>

#define LEN   4096
#define EMB   300
#define HALF  256
#define G4    1024   // 4*HALF
#define HID   512
#define OUT_N 20

#if defined(__has_builtin)
#  if __has_builtin(__builtin_amdgcn_sdot4)
#    define HAVE_SDOT4 1
#  endif
#  if __has_builtin(__builtin_amdgcn_rcpf)
#    define RCPF(x) __builtin_amdgcn_rcpf(x)
#  endif
#endif
#ifndef RCPF
#  define RCPF(x) (1.0f/(x))
#endif

__device__ __forceinline__ int dot4(int a, int b, int c){
#ifdef HAVE_SDOT4
  return __builtin_amdgcn_sdot4(a, b, c, false);
#else
  c += (int)(signed char)(a)     * (int)(signed char)(b);
  c += (int)(signed char)(a>>8)  * (int)(signed char)(b>>8);
  c += (int)(signed char)(a>>16) * (int)(signed char)(b>>16);
  c += (int)(a>>24)              * (int)(b>>24);
  return c;
#endif
}

__device__ __forceinline__ float sigm_(float x){ return RCPF(1.f + __expf(-x)); }
__device__ __forceinline__ float tanh_(float x){ return 2.f*RCPF(1.f + __expf(-2.f*x)) - 1.f; }
__device__ __forceinline__ float bf2f(unsigned short u){ return __uint_as_float(((unsigned)u)<<16); }

// lane-pair swap (xor 1) via DPP quad_perm[1,0,3,2] = 0xB1 — pure VALU
__device__ __forceinline__ int dpp1i(int x){
  return __builtin_amdgcn_mov_dpp(x, 0xB1, 0xF, 0xF, true);
}
__device__ __forceinline__ float dpp1f(float x){
  return __int_as_float(dpp1i(__float_as_int(x)));
}

// ---------------- prep: quantize Whh rows to i8 + bias sums -----------------
__global__ void prep_quant(const float* __restrict__ WhhF, const float* __restrict__ WhhB,
    const float* __restrict__ bihF, const float* __restrict__ bhhF,
    const float* __restrict__ bihB, const float* __restrict__ bhhB,
    signed char* __restrict__ Wq, float* __restrict__ wsc, float* __restrict__ bsum)
{
  int r = blockIdx.x*256 + threadIdx.x;
  if (r >= 2*G4) return;
  int dir = r >> 10, row = r & 1023;
  const float4* Wr = (const float4*)((dir ? WhhB : WhhF) + (size_t)row*HALF);
  float m = 0.f;
  #pragma unroll 4
  for (int k=0;k<HALF/4;k++){
    float4 v = Wr[k];
    m = fmaxf(m, fmaxf(fmaxf(fabsf(v.x),fabsf(v.y)), fmaxf(fabsf(v.z),fabsf(v.w))));
  }
  float inv = 127.f / fmaxf(m, 1e-30f);
  int* q = (int*)(Wq + (size_t)r*HALF);
  #pragma unroll 4
  for (int k=0;k<HALF/4;k++){
    float4 v = Wr[k];
    int b0 = __float2int_rn(v.x*inv); b0 = b0>127?127:(b0<-127?-127:b0);
    int b1 = __float2int_rn(v.y*inv); b1 = b1>127?127:(b1<-127?-127:b1);
    int b2 = __float2int_rn(v.z*inv); b2 = b2>127?127:(b2<-127?-127:b2);
    int b3 = __float2int_rn(v.w*inv); b3 = b3>127?127:(b3<-127?-127:b3);
    q[k] = (b0&255) | ((b1&255)<<8) | ((b2&255)<<16) | ((b3&255)<<24);
  }
  wsc[r]  = (m/127.f)*(1.f/127.f);        // scale for (i32 dot) -> f32
  bsum[r] = dir ? (bihB[row]+bhhB[row]) : (bihF[row]+bhhF[row]);
}

// ---------------- Wv_ae = AE @ W_v_a^T + b_v_a  [20,512] --------------------
__global__ void wv_kernel(const float* __restrict__ AE, const float* __restrict__ Wv,
                          const float* __restrict__ bv, float* __restrict__ WvAE)
{
  __shared__ float ae[EMB];
  const int o = blockIdx.x, tid = threadIdx.x;
  for (int k=tid;k<EMB;k+=256) ae[k] = AE[(size_t)o*EMB+k];
  __syncthreads();
  for (int j=tid;j<HID;j+=256){
    const float* wr = Wv + (size_t)j*EMB;
    float d = 0.f;
    for (int k=0;k<EMB;k++) d += ae[k]*wr[k];
    WvAE[(size_t)o*HID + j] = d + bv[j];
  }
}

// ---- generic C[M,N] = A[idx(m),:K] * B[n,:K]^T + bias[n]; out f32 or bf16 ---
// gperm: permute output column g*256+j -> j*4+g (gate-interleaved pre layout)
__global__ __launch_bounds__(256) void gemm_tn(
    const float* __restrict__ A, int lda, const int* __restrict__ idx,
    const float* __restrict__ B, int ldb, const float* __restrict__ bias,
    float* __restrict__ Cf, __hip_bfloat16* __restrict__ Cb, int ldc,
    int M, int N, int K, int gperm)
{
  __shared__ __align__(16) float As[16][68];
  __shared__ __align__(16) float Bs[16][68];
  const int tid = threadIdx.x;
  const int bm = blockIdx.x<<6, bn = blockIdx.y<<6;
  const int lm = tid>>2;            // 0..63 row loaded by this thread
  const int lk = (tid&3)<<2;        // 0,4,8,12 k offset
  const int ty = tid>>4, tx = tid&15;
  int arow = bm + lm;
  if (idx) arow = idx[arow];
  const float* Ap = A + (size_t)arow*lda + lk;
  const float* Bp = B + (size_t)(bn+lm)*ldb + lk;
  float acc[4][4];
  #pragma unroll
  for (int i=0;i<4;i++)
    #pragma unroll
    for (int j=0;j<4;j++) acc[i][j]=0.f;

  for (int k0=0;k0<K;k0+=16){
    float4 av, bv;
    if (k0+16 <= K){
      av = *(const float4*)(Ap+k0);
      bv = *(const float4*)(Bp+k0);
    } else {
      float a0[4], b0[4];
      #pragma unroll
      for (int j=0;j<4;j++){
        int kk = k0+lk+j;
        a0[j] = (kk<K)? Ap[k0+j] : 0.f;
        b0[j] = (kk<K)? Bp[k0+j] : 0.f;
      }
      av = make_float4(a0[0],a0[1],a0[2],a0[3]);
      bv = make_float4(b0[0],b0[1],b0[2],b0[3]);
    }
    __syncthreads();
    As[lk+0][lm]=av.x; As[lk+1][lm]=av.y; As[lk+2][lm]=av.z; As[lk+3][lm]=av.w;
    Bs[lk+0][lm]=bv.x; Bs[lk+1][lm]=bv.y; Bs[lk+2][lm]=bv.z; Bs[lk+3][lm]=bv.w;
    __syncthreads();
    #pragma unroll
    for (int kk=0;kk<16;kk++){
      const float4 a = *(const float4*)(&As[kk][ty<<2]);
      const float4 b = *(const float4*)(&Bs[kk][tx<<2]);
      acc[0][0]+=a.x*b.x; acc[0][1]+=a.x*b.y; acc[0][2]+=a.x*b.z; acc[0][3]+=a.x*b.w;
      acc[1][0]+=a.y*b.x; acc[1][1]+=a.y*b.y; acc[1][2]+=a.y*b.z; acc[1][3]+=a.y*b.w;
      acc[2][0]+=a.z*b.x; acc[2][1]+=a.z*b.y; acc[2][2]+=a.z*b.z; acc[2][3]+=a.z*b.w;
      acc[3][0]+=a.w*b.x; acc[3][1]+=a.w*b.y; acc[3][2]+=a.w*b.z; acc[3][3]+=a.w*b.w;
    }
  }
  const int cm = bm+(ty<<2), cn = bn+(tx<<2);
  #pragma unroll
  for (int i=0;i<4;i++){
    #pragma unroll
    for (int j=0;j<4;j++){
      float v = acc[i][j] + (bias ? bias[cn+j] : 0.f);
      int col = cn+j;
      int pc = gperm ? (((col&255)<<2) | (col>>8)) : col;
      if (Cb) Cb[(size_t)(cm+i)*ldc + pc] = __float2bfloat16(v);
      else    Cf[(size_t)(cm+i)*ldc + pc] = v;
    }
  }
}

// -------------------- persistent bidirectional LSTM scan --------------------
// R11 structure (best: 3116us scan, absmax 0.00195). 2 blocks, 512 threads
// (8 waves, 2/SIMD). Thread (j=tid>>1, q2=tid&1) owns all 4 gate rows of unit
// j over k-half [128*q2,128*q2+128): 128 i8-packed weight ints as plain C
// locals. CHANGE vs R12: ~97KB of padded static LDS forces 1 block/CU, so the
// register allocator's occupancy-from-LDS target drops to 2 waves/SIMD ->
// 256-VGPR budget -> the 128 weight dwords (+~50 working regs) fit entirely
// in arch VGPRs, killing the spill-to-AGPR restores (~37% of scan VALU work)
// that the num_vgpr/num_agpr/waves_per_eu attributes all failed to remove.
__global__ __attribute__((amdgpu_flat_work_group_size(512,512), amdgpu_waves_per_eu(2,2)))
void lstm_scan(
    const __hip_bfloat16* __restrict__ preF,   // [LEN][1024] gate-permuted [s][4j+g]
    const __hip_bfloat16* __restrict__ preB,
    const signed char* __restrict__ Wq,        // [2][1024][256] rows g*256+j
    const float* __restrict__ wsc,             // [2][1024]
    float* __restrict__ hs, float* __restrict__ ht)
{
  const int dir = blockIdx.x;
  const int tid = threadIdx.x;   // 0..511
  const int j  = tid >> 1;       // unit 0..255
  const int q2 = tid & 1;        // k-half 0..1
  __shared__ int hq[2][64];      // double-buffered 256 x i8 h
  __shared__ int pad_[24320];    // ~95KB occupancy limiter: 1 block/CU
  ((volatile int*)pad_)[tid] = 0;  // keep-alive; never read meaningfully

  const signed char* wp = Wq + (size_t)dir*G4*HALF;
  const int4* p0 = (const int4*)(wp + (size_t)(0*HALF + j)*HALF + q2*128);
  const int4* p1 = (const int4*)(wp + (size_t)(1*HALF + j)*HALF + q2*128);
  const int4* p2 = (const int4*)(wp + (size_t)(2*HALF + j)*HALF + q2*128);
  const int4* p3 = (const int4*)(wp + (size_t)(3*HALF + j)*HALF + q2*128);
  int4 wA0=p0[0],wA1=p0[1],wA2=p0[2],wA3=p0[3],wA4=p0[4],wA5=p0[5],wA6=p0[6],wA7=p0[7];
  int4 wB0=p1[0],wB1=p1[1],wB2=p1[2],wB3=p1[3],wB4=p1[4],wB5=p1[5],wB6=p1[6],wB7=p1[7];
  int4 wC0=p2[0],wC1=p2[1],wC2=p2[2],wC3=p2[3],wC4=p2[4],wC5=p2[5],wC6=p2[6],wC7=p2[7];
  int4 wD0=p3[0],wD1=p3[1],wD2=p3[2],wD3=p3[3],wD4=p3[4],wD5=p3[5],wD6=p3[6],wD7=p3[7];
#define PIN(v) asm volatile("" : "+v"(v.x),"+v"(v.y),"+v"(v.z),"+v"(v.w))
  PIN(wA0);PIN(wA1);PIN(wA2);PIN(wA3);PIN(wA4);PIN(wA5);PIN(wA6);PIN(wA7);
  PIN(wB0);PIN(wB1);PIN(wB2);PIN(wB3);PIN(wB4);PIN(wB5);PIN(wB6);PIN(wB7);
  PIN(wC0);PIN(wC1);PIN(wC2);PIN(wC3);PIN(wC4);PIN(wC5);PIN(wC6);PIN(wC7);
  PIN(wD0);PIN(wD1);PIN(wD2);PIN(wD3);PIN(wD4);PIN(wD5);PIN(wD6);PIN(wD7);
#undef PIN

  // lane q2 computes gates {2*q2, 2*q2+1}: lane0 -> (i,f), lane1 -> (g~,o)
  const float scA = wsc[dir*G4 + (2*q2+0)*HALF + j];
  const float scB = wsc[dir*G4 + (2*q2+1)*HALF + j];
  const float eK0 = q2 ? -2.f : -1.f;    // slot0: sigmoid (lane0) / tanh (lane1)
  const float aM0 = q2 ?  2.f :  1.f;
  const float aB0 = q2 ? -1.f :  0.f;

  const int t0 = dir ? (LEN-1) : 0;
  const int pstep = dir ? -(G4/2) : (G4/2);     // row stride in uints
  const unsigned* pp = (const unsigned*)(dir ? preB : preF) + (size_t)t0*(G4/2) + tid;
  float* hsp = hs + (size_t)t0*HID + dir*HALF + j;
  const int hstep = dir ? -HID : HID;

  if (tid < 64) hq[0][tid] = 0;
  float c = 0.f;
  unsigned pv = *pp;
  __syncthreads();

  for (int s=0;s<LEN;s++){
    unsigned pnext = 0;
    if (s < LEN-1){ pp += pstep; pnext = *pp; }
    const int4* hb = (const int4*)(&hq[s&1][0]) + q2*8;
    int a0=0,a1=0,a2=0,a3=0;
#define CHUNK(i, A,B,C,D) { int4 hv = hb[i]; \
    a0=dot4(A.x,hv.x,a0); a0=dot4(A.y,hv.y,a0); a0=dot4(A.z,hv.z,a0); a0=dot4(A.w,hv.w,a0); \
    a1=dot4(B.x,hv.x,a1); a1=dot4(B.y,hv.y,a1); a1=dot4(B.z,hv.z,a1); a1=dot4(B.w,hv.w,a1); \
    a2=dot4(C.x,hv.x,a2); a2=dot4(C.y,hv.y,a2); a2=dot4(C.z,hv.z,a2); a2=dot4(C.w,hv.w,a2); \
    a3=dot4(D.x,hv.x,a3); a3=dot4(D.y,hv.y,a3); a3=dot4(D.z,hv.z,a3); a3=dot4(D.w,hv.w,a3); }
    CHUNK(0, wA0,wB0,wC0,wD0)
    CHUNK(1, wA1,wB1,wC1,wD1)
    CHUNK(2, wA2,wB2,wC2,wD2)
    CHUNK(3, wA3,wB3,wC3,wD3)
    CHUNK(4, wA4,wB4,wC4,wD4)
    CHUNK(5, wA5,wB5,wC5,wD5)
    CHUNK(6, wA6,wB6,wC6,wD6)
    CHUNK(7, wA7,wB7,wC7,wD7)
#undef CHUNK
    // ---- DPP pair transpose-reduce over the lane pair ----
    // lane0 wants full a0,a1 (i,f); lane1 wants full a2,a3 (g~,o)
    int r0 = dpp1i(q2 ? a0 : a2);
    int s0 = (q2 ? a2 : a0) + r0;          // lane0: i pre-sum; lane1: g~ pre-sum
    int r1 = dpp1i(q2 ? a1 : a3);
    int s1 = (q2 ? a3 : a1) + r1;          // lane0: f pre-sum; lane1: o pre-sum
    // ---- 2 nonlinearities per thread ----
    float g0v = bf2f((unsigned short)(pv & 0xffffu))  + (float)s0*scA;
    float g1v = bf2f((unsigned short)(pv >> 16))      + (float)s1*scB;
    float y0  = RCPF(1.f + __expf(eK0 * g0v));
    float act0 = fmaf(aM0, y0, aB0);       // lane0: i ; lane1: g~
    float act1 = sigm_(g1v);               // lane0: f ; lane1: o
    // ---- bring (g~, o) to lane0 via DPP ----
    float gg = dpp1f(act0);                // lane0: g~
    float oo = dpp1f(act1);                // lane0: o
    if (q2 == 0){
      c = fmaf(act1, c, act0 * gg);
      float h = oo * tanh_(c);
      *hsp = h;
      ((signed char*)&hq[(s+1)&1][0])[j] = (signed char)__float2int_rn(h * 127.f);
      if (s == LEN-1) ht[dir*HALF + j] = h;
    }
    hsp += hstep;
    pv = pnext;
    __syncthreads();
  }
}

// ---------------- xw = ht @ W_x_a^T + b_x_a [512] ---------------------------
__global__ __launch_bounds__(512) void xw_kernel(const float* __restrict__ ht,
    const float* __restrict__ Wx, const float* __restrict__ bx, float* __restrict__ xw)
{
  __shared__ float h[HID];
  const int tid = threadIdx.x;
  h[tid] = ht[tid];
  __syncthreads();
  const float* wr = Wx + (size_t)tid*HID;
  float d = 0.f;
  for (int k=0;k<HID;k++) d += h[k]*wr[k];
  xw[tid] = d + bx[tid];
}

// ------- scores[o,l] = w_a . tanh(Wh_out[l] + Wv_ae[o]) + b_w_a -------------
__global__ __launch_bounds__(256) void scores_kernel(
    const float* __restrict__ WhOut, const float* __restrict__ WvAE,
    const float* __restrict__ wa, const float* __restrict__ bwa,
    float* __restrict__ scores)
{
  __shared__ float red[4];
  const int l = blockIdx.x, tid = threadIdx.x;
  const int lane = tid & 63, wv = tid >> 6;
  const float wl0 = WhOut[(size_t)l*HID + tid];
  const float wl1 = WhOut[(size_t)l*HID + 256 + tid];
  const float wa0 = wa[tid], wa1 = wa[256+tid];
  const float bb = bwa[0];
  for (int o=0;o<OUT_N;o++){
    float v = wa0*tanh_(wl0 + WvAE[o*HID+tid]) + wa1*tanh_(wl1 + WvAE[o*HID+256+tid]);
    #pragma unroll
    for (int m=32;m;m>>=1) v += __shfl_xor(v, m, 64);
    if (lane==0) red[wv] = v;
    __syncthreads();
    if (tid==0) scores[(size_t)o*LEN + l] = red[0]+red[1]+red[2]+red[3] + bb;
    __syncthreads();
  }
}

// ------- softmax over l (per o) + r[o] = weights @ output2 ------------------
__global__ __launch_bounds__(512) void softmax_wsum(
    const float* __restrict__ scores, const float* __restrict__ hs, float* __restrict__ ratt)
{
  __shared__ float sm[LEN];
  __shared__ float red[8];
  __shared__ float bc[2];
  const int o = blockIdx.x, tid = threadIdx.x;
  const int lane = tid & 63, wv = tid >> 6;
  for (int l=tid;l<LEN;l+=512) sm[l] = scores[(size_t)o*LEN + l];
  __syncthreads();
  float mx = -1e30f;
  for (int l=tid;l<LEN;l+=512) mx = fmaxf(mx, sm[l]);
  #pragma unroll
  for (int m=32;m;m>>=1) mx = fmaxf(mx, __shfl_xor(mx, m, 64));
  if (lane==0) red[wv] = mx;
  __syncthreads();
  if (tid==0){ float m0=red[0]; for (int i=1;i<8;i++) m0=fmaxf(m0,red[i]); bc[0]=m0; }
  __syncthreads();
  const float m0 = bc[0];
  float s = 0.f;
  for (int l=tid;l<LEN;l+=512){ float e = __expf(sm[l]-m0); sm[l]=e; s+=e; }
  #pragma unroll
  for (int m=32;m;m>>=1) s += __shfl_xor(s, m, 64);
  if (lane==0) red[wv] = s;
  __syncthreads();
  if (tid==0){ float z=0.f; for (int i=0;i<8;i++) z+=red[i]; bc[1] = 1.f/z; }
  __syncthreads();
  const float rz = bc[1];
  float acc = 0.f;
  const float* hp = hs + tid;
  for (int l=0;l<LEN;l++) acc += sm[l]*hp[(size_t)l*HID];
  ratt[(size_t)o*HID + tid] = acc*rz;
}

// ------- out[o] = sigmoid( dec_W[o] . tanh(r W_p^T + b_p + xw) + dec_b ) ----
__global__ __launch_bounds__(256) void final_kernel(
    const float* __restrict__ ratt, const float* __restrict__ Wp, const float* __restrict__ bp,
    const float* __restrict__ xw, const float* __restrict__ decW, const float* __restrict__ decb,
    float* __restrict__ outp)
{
  __shared__ float rv[HID];
  __shared__ float rr[HID];
  __shared__ float red[4];
  const int o = blockIdx.x, tid = threadIdx.x;
  const int lane = tid & 63, wv = tid >> 6;
  rv[tid]     = ratt[(size_t)o*HID + tid];
  rv[256+tid] = ratt[(size_t)o*HID + 256 + tid];
  __syncthreads();
  #pragma unroll
  for (int jj=0;jj<2;jj++){
    int j = tid + jj*256;
    const float* wr = Wp + (size_t)j*HID;
    float d = 0.f;
    for (int k=0;k<HID;k++) d += rv[k]*wr[k];
    rr[j] = tanh_(d + bp[j] + xw[j]);
  }
  __syncthreads();
  float v = rr[tid]*decW[(size_t)o*HID+tid] + rr[256+tid]*decW[(size_t)o*HID+256+tid];
  #pragma unroll
  for (int m=32;m;m>>=1) v += __shfl_xor(v, m, 64);
  if (lane==0) red[wv] = v;
  __syncthreads();
  if (tid==0) outp[o] = sigm_(red[0]+red[1]+red[2]+red[3] + decb[o]);
}

// ---------------------------------------------------------------------------
extern "C" void kernel_launch(void* const* d_in, const int* in_sizes, int n_in,
                              void* d_out, int out_size, void* d_ws, size_t ws_size,
                              hipStream_t stream)
{
  (void)in_sizes; (void)n_in; (void)out_size; (void)ws_size;
  const int*   sent  = (const int*)  d_in[0];
  const float* embed = (const float*)d_in[1];
  const float* WihF  = (const float*)d_in[2];
  const float* WhhF  = (const float*)d_in[3];
  const float* bihF  = (const float*)d_in[4];
  const float* bhhF  = (const float*)d_in[5];
  const float* WihB  = (const float*)d_in[6];
  const float* WhhB  = (const float*)d_in[7];
  const float* bihB  = (const float*)d_in[8];
  const float* bhhB  = (const float*)d_in[9];
  const float* AE    = (const float*)d_in[10];
  const float* W_h   = (const float*)d_in[11];
  const float* b_h   = (const float*)d_in[12];
  const float* W_v   = (const float*)d_in[13];
  const float* b_v   = (const float*)d_in[14];
  const float* w_a   = (const float*)d_in[15];
  const float* b_w   = (const float*)d_in[16];
  const float* W_p   = (const float*)d_in[17];
  const float* b_p   = (const float*)d_in[18];
  const float* W_x   = (const float*)d_in[19];
  const float* b_x   = (const float*)d_in[20];
  const float* decW  = (const float*)d_in[21];
  const float* decb  = (const float*)d_in[22];
  float* outp = (float*)d_out;

  char* ws = (char*)d_ws;
  size_t off = 0;
  auto alloc = [&](size_t n){ size_t p = off; off += (n + 255) & ~(size_t)255; return p; };
  __hip_bfloat16* preF  = (__hip_bfloat16*)(ws + alloc((size_t)LEN*G4*2));
  __hip_bfloat16* preB  = (__hip_bfloat16*)(ws + alloc((size_t)LEN*G4*2));
  float*          hsbuf = (float*)        (ws + alloc((size_t)LEN*HID*4));
  float*          WhOut = (float*)        (ws + alloc((size_t)LEN*HID*4));
  signed char*    Wq    = (signed char*)  (ws + alloc((size_t)2*G4*HALF));
  float*          wsc   = (float*)        (ws + alloc((size_t)2*G4*4));
  float*          bsum  = (float*)        (ws + alloc((size_t)2*G4*4));
  float*          htv   = (float*)        (ws + alloc((size_t)HID*4));
  float*          WvAE  = (float*)        (ws + alloc((size_t)OUT_N*HID*4));
  float*          xw    = (float*)        (ws + alloc((size_t)HID*4));
  float*          scor  = (float*)        (ws + alloc((size_t)OUT_N*LEN*4));
  float*          ratt  = (float*)        (ws + alloc((size_t)OUT_N*HID*4));

  // prep
  prep_quant<<<8, 256, 0, stream>>>(WhhF, WhhB, bihF, bhhF, bihB, bhhB, Wq, wsc, bsum);
  wv_kernel<<<OUT_N, 256, 0, stream>>>(AE, W_v, b_v, WvAE);

  // pre = gather(embed, sent) @ Wih^T + (bih+bhh), bf16, gate-permuted cols
  gemm_tn<<<dim3(LEN/64, G4/64), 256, 0, stream>>>(
      embed, EMB, sent, WihF, EMB, bsum,        nullptr, preF, G4, LEN, G4, EMB, 1);
  gemm_tn<<<dim3(LEN/64, G4/64), 256, 0, stream>>>(
      embed, EMB, sent, WihB, EMB, bsum + G4,   nullptr, preB, G4, LEN, G4, EMB, 1);

  // sequential bidirectional scan (2 persistent blocks, 512 threads each)
  lstm_scan<<<2, 512, 0, stream>>>(preF, preB, Wq, wsc, hsbuf, htv);

  // Wh_out = output2 @ W_h_a^T + b_h_a
  gemm_tn<<<dim3(LEN/64, HID/64), 256, 0, stream>>>(
      hsbuf, HID, nullptr, W_h, HID, b_h, WhOut, nullptr, HID, LEN, HID, HID, 0);

  xw_kernel<<<1, 512, 0, stream>>>(htv, W_x, b_x, xw);
  scores_kernel<<<LEN, 256, 0, stream>>>(WhOut, WvAE, w_a, b_w, scor);
  softmax_wsum<<<OUT_N, 512, 0, stream>>>(scor, hsbuf, ratt);
  final_kernel<<<OUT_N, 256, 0, stream>>>(ratt, W_p, b_p, xw, decW, decb, outp);
}